// Round 7
// baseline (400.161 us; speedup 1.0000x reference)
//
#include <hip/hip_runtime.h>
#include <math.h>

#define K_RBF 32
#define H_DIM 64
#define TBL 4096
#define D_MAX 16.0f
#define N_NODES 49152
#define N_EDGES 786432
#define N_GRAPHS 8
#define NODES_PER_GRAPH 6144
#define EV_A3_TO_GPA 160.21766208f
#define LOG2E 1.44269504088896f

// out layout: energies[8] | forces[147456] | stresses[72] | hessian[1]
#define OUT_FORCES 8
#define OUT_STRESS 147464
#define OUT_TAIL_N 81

// fused geometry: 512 blocks x 512 threads, __launch_bounds__(512,6) ->
// >=3 blocks/CU -> 768 slots >= 512 blocks -> ALL co-resident -> software
// grid barrier is deadlock-free.
#define NBLOCKS 512
#define NTHREADS 512
#define EDGES_PER_THREAD 3            // 512*512*3 = 786432
#define BLK_PER_GRAPH 64              // 98304 edges/graph / 1536

// force binning: chunk = node >> 7 (128 nodes, 1.5 KB LDS acc)
#define CHUNK_NODES  128
#define CHUNK_FLOATS 384
#define N_CHUNKS     384
#define REC_CAP      4608             // mean 4096, sigma 64 -> +8 sigma

#define MAGIC 0x13579BDF

// ws layout: tab 32 KB | ctl 2 KB | records
#define OFF_TAB 0u
#define OFF_CTL 32768u
// ctl ints: [0] init-flag [1] barA [2] barB [3] ticket [16..399] gcnt[384]
#define OFF_REC 34816u
#define WS_NEED (OFF_REC + (size_t)N_CHUNKS * REC_CAP * 16u)   // ~28.3 MB

// software grid barrier: all NBLOCKS co-resident (see launch_bounds proof).
// Bounded spin: on timeout we proceed (absmax will flag it) instead of hanging.
__device__ __forceinline__ void gbar(int* c) {
    __syncthreads();
    if (threadIdx.x == 0) {
        __hip_atomic_fetch_add(c, 1, __ATOMIC_ACQ_REL, __HIP_MEMORY_SCOPE_AGENT);
        for (int k = 0; k < 20000000; ++k) {
            if (__hip_atomic_load(c, __ATOMIC_ACQUIRE, __HIP_MEMORY_SCOPE_AGENT)
                >= NBLOCKS) break;
            __builtin_amdgcn_s_sleep(2);
        }
    }
    __syncthreads();
}

__global__ __launch_bounds__(NTHREADS, 6) void fused_all(
    const float* __restrict__ pos, const float* __restrict__ bond,
    const int* __restrict__ src, const int* __restrict__ dst,
    const float* __restrict__ volume, const float* __restrict__ centers,
    const float* __restrict__ W1, const float* __restrict__ b1,
    const float* __restrict__ W2, const float* __restrict__ b2,
    const float* __restrict__ W3, const float* __restrict__ b3,
    float2* __restrict__ tab, int* __restrict__ ctl,
    float4* __restrict__ recs, float* __restrict__ out)
{
    __shared__ float W2s[H_DIM * 65];          // 16.6 KB
    __shared__ int   cnt[N_CHUNKS];
    __shared__ int   basech[N_CHUNKS];
    __shared__ float red[8][10];
    __shared__ float acc[CHUNK_FLOATS];        // 1.5 KB
    __shared__ int   sticket;

    const int t = threadIdx.x, b = blockIdx.x;
    const int lane = t & 63, wave = t >> 6;
    int* gcnt = ctl + 16;

    // ---------- init (block 0 only; released via flag) ----------
    if (b == 0) {
        if (t < N_CHUNKS) gcnt[t] = 0;
        if (t == 400) { ctl[1] = 0; ctl[2] = 0; ctl[3] = 0; }
        if (t < N_GRAPHS) out[t] = 0.f;                       // energies
        else if (t < OUT_TAIL_N) out[3 * N_NODES + t] = 0.f;  // stress+hessian
        __threadfence();
        __syncthreads();
        if (t == 0)
            __hip_atomic_store(ctl, MAGIC, __ATOMIC_RELEASE,
                               __HIP_MEMORY_SCOPE_AGENT);
    }

    // ---------- phase 0: table (entry = b*8 + wave; 512*8 = 4096) ----------
    for (int idx = t; idx < H_DIM * H_DIM; idx += NTHREADS)
        W2s[(idx >> 6) * 65 + (idx & 63)] = W2[idx];
    __syncthreads();
    {
        int i = b * 8 + wave;
        float d = (float)i * (D_MAX / (float)TBL);
        float z1 = b1[lane], u = 0.f;
#pragma unroll
        for (int k = 0; k < K_RBF; ++k) {
            float tc = d - centers[k];
            float e  = exp2f(-tc * tc * LOG2E);      // exp(-t^2)
            float w  = W1[k * H_DIM + lane];
            z1 = fmaf(e, w, z1);
            u  = fmaf(-2.f * tc * e, w, u);
        }
        float s1  = 1.f / (1.f + exp2f(-z1 * LOG2E));
        float h1  = z1 * s1;
        float ds1 = s1 * fmaf(z1, 1.f - s1, 1.f);

        float z2 = b2[lane];
#pragma unroll
        for (int h = 0; h < H_DIM; ++h)
            z2 = fmaf(__shfl(h1, h, 64), W2s[h * 65 + lane], z2);

        float s2  = 1.f / (1.f + exp2f(-z2 * LOG2E));
        float w3  = W3[lane];
        float Fp  = z2 * s2 * w3;
        float dz2 = w3 * s2 * fmaf(z2, 1.f - s2, 1.f);

        float dh1 = 0.f;
#pragma unroll
        for (int j = 0; j < H_DIM; ++j)
            dh1 = fmaf(__shfl(dz2, j, 64), W2s[lane * 65 + j], dh1);

        float Gp = dh1 * ds1 * u;
#pragma unroll
        for (int m = 32; m > 0; m >>= 1) {
            Fp += __shfl_xor(Fp, m, 64);
            Gp += __shfl_xor(Gp, m, 64);
        }
        if (lane == 0) tab[i] = make_float2(Fp + b3[0], Gp);
    }

    // wait for init flag (non-block-0), then grid barrier A (table done)
    if (b != 0) {
        if (t == 0) {
            for (int k = 0; k < 20000000; ++k) {
                if (__hip_atomic_load(ctl, __ATOMIC_ACQUIRE,
                                      __HIP_MEMORY_SCOPE_AGENT) == MAGIC) break;
                __builtin_amdgcn_s_sleep(2);
            }
        }
        __syncthreads();
    }
    gbar(ctl + 1);

    // ---------- phase 1: edges -> records + energy/stress ----------
    if (t < N_CHUNKS) cnt[t] = 0;
    __syncthreads();

    const int g = b >> 6;                        // BLK_PER_GRAPH = 64
    const int base_e = b * (NTHREADS * EDGES_PER_THREAD);

    float vacc[10];
#pragma unroll
    for (int q = 0; q < 10; ++q) vacc[q] = 0.f;

    int   edi[EDGES_PER_THREAD], esi[EDGES_PER_THREAD];
    int   es0[EDGES_PER_THREAD], es1[EDGES_PER_THREAD];
    float egx[EDGES_PER_THREAD], egy[EDGES_PER_THREAD], egz[EDGES_PER_THREAD];

#pragma unroll
    for (int i = 0; i < EDGES_PER_THREAD; ++i) {
        int e  = base_e + i * NTHREADS + t;
        int si = src[e], di = dst[e];
        float bx = bond[3 * e + 0], by = bond[3 * e + 1], bz = bond[3 * e + 2];
        float dx = bx + pos[3 * di + 0] - pos[3 * si + 0];
        float dy = by + pos[3 * di + 1] - pos[3 * si + 1];
        float dz = bz + pos[3 * di + 2] - pos[3 * si + 2];
        float d  = sqrtf(fmaf(dx, dx, fmaf(dy, dy, fmaf(dz, dz, 1e-12f))));

        float tt  = fminf(d * ((float)TBL / D_MAX), (float)(TBL - 1));
        int   ix  = min((int)tt, TBL - 2);
        float fr  = tt - (float)ix;
        float2 ta = tab[ix], tb2 = tab[ix + 1];
        float F = fmaf(fr, tb2.x - ta.x, ta.x);
        float G = fmaf(fr, tb2.y - ta.y, ta.y);

        float scl = G / d;                       // gbv = (dE/dd)/d * disp
        float gx = scl * dx, gy = scl * dy, gz = scl * dz;
        egx[i] = gx; egy[i] = gy; egz[i] = gz;
        edi[i] = di; esi[i] = si;
        es0[i] = atomicAdd(&cnt[di >> 7], 1);
        es1[i] = atomicAdd(&cnt[si >> 7], 1);

        vacc[0] += F;
        vacc[1] = fmaf(bx, gx, vacc[1]); vacc[2] = fmaf(bx, gy, vacc[2]);
        vacc[3] = fmaf(bx, gz, vacc[3]); vacc[4] = fmaf(by, gx, vacc[4]);
        vacc[5] = fmaf(by, gy, vacc[5]); vacc[6] = fmaf(by, gz, vacc[6]);
        vacc[7] = fmaf(bz, gx, vacc[7]); vacc[8] = fmaf(bz, gy, vacc[8]);
        vacc[9] = fmaf(bz, gz, vacc[9]);
    }
    __syncthreads();
    if (t < N_CHUNKS) basech[t] = atomicAdd(&gcnt[t], cnt[t]);
    __syncthreads();
#pragma unroll
    for (int i = 0; i < EDGES_PER_THREAD; ++i) {
        int c0 = edi[i] >> 7, c1 = esi[i] >> 7;
        int p0 = basech[c0] + es0[i];
        int p1 = basech[c1] + es1[i];
        if (p0 < REC_CAP)   // dst gets -g (forces = -gpos)
            recs[(size_t)c0 * REC_CAP + p0] =
                make_float4(-egx[i], -egy[i], -egz[i],
                            __int_as_float(edi[i] & (CHUNK_NODES - 1)));
        if (p1 < REC_CAP)   // src gets +g
            recs[(size_t)c1 * REC_CAP + p1] =
                make_float4(egx[i], egy[i], egz[i],
                            __int_as_float(esi[i] & (CHUNK_NODES - 1)));
    }

    // block-level energy+stress reduce (all edges in block share graph g)
#pragma unroll
    for (int q = 0; q < 10; ++q) {
        float x = vacc[q];
#pragma unroll
        for (int m = 32; m > 0; m >>= 1) x += __shfl_xor(x, m, 64);
        vacc[q] = x;
    }
    if (lane == 0)
#pragma unroll
        for (int q = 0; q < 10; ++q) red[wave][q] = vacc[q];
    __syncthreads();
    if (t < 10) {
        float tot = 0.f;
#pragma unroll
        for (int k = 0; k < 8; ++k) tot += red[k][t];
        if (t == 0) atomicAdd(out + g, tot);
        else {
            float vol = volume[g * NODES_PER_GRAPH];
            atomicAdd(out + OUT_STRESS + g * 9 + (t - 1),
                      tot * (EV_A3_TO_GPA / vol));
        }
    }
    __threadfence();
    gbar(ctl + 2);

    // ---------- phase 2: scatter chunks via ticket (load-balanced) ----------
    for (;;) {
        if (t == 0) sticket = atomicAdd(ctl + 3, 1);
        __syncthreads();
        int c = sticket;
        if (c >= N_CHUNKS) break;

        if (t < CHUNK_FLOATS) acc[t] = 0.f;
        __syncthreads();

        int total = min(gcnt[c], REC_CAP);
        const float4* seg = recs + (size_t)c * REC_CAP;
        for (int r = t; r < total; r += NTHREADS) {
            float4 rec = seg[r];
            int li = 3 * __float_as_int(rec.w);
            atomicAdd(&acc[li + 0], rec.x);
            atomicAdd(&acc[li + 1], rec.y);
            atomicAdd(&acc[li + 2], rec.z);
        }
        __syncthreads();

        if (t < CHUNK_FLOATS / 4) {
            float4* dst4 = (float4*)(out + OUT_FORCES + c * CHUNK_FLOATS);
            dst4[t] = ((const float4*)acc)[t];
        }
        __syncthreads();
    }
}

// ---------------- fallback (ws too small): 2-dispatch atomic path ----------
__global__ __launch_bounds__(256) void build_table_fb(
    const float* __restrict__ centers,
    const float* __restrict__ W1, const float* __restrict__ b1,
    const float* __restrict__ W2, const float* __restrict__ b2,
    const float* __restrict__ W3, const float* __restrict__ b3,
    float2* __restrict__ tab)
{
    __shared__ float W2s[H_DIM * 65];
    for (int idx = threadIdx.x; idx < H_DIM * H_DIM; idx += 256)
        W2s[(idx >> 6) * 65 + (idx & 63)] = W2[idx];
    __syncthreads();

    int lane = threadIdx.x & 63;
    int i    = blockIdx.x * 4 + (threadIdx.x >> 6);
    float d  = (float)i * (D_MAX / (float)TBL);

    float z1 = b1[lane], u = 0.f;
#pragma unroll
    for (int k = 0; k < K_RBF; ++k) {
        float tc = d - centers[k];
        float e  = exp2f(-tc * tc * LOG2E);
        float w  = W1[k * H_DIM + lane];
        z1 = fmaf(e, w, z1);
        u  = fmaf(-2.f * tc * e, w, u);
    }
    float s1  = 1.f / (1.f + exp2f(-z1 * LOG2E));
    float h1  = z1 * s1;
    float ds1 = s1 * fmaf(z1, 1.f - s1, 1.f);

    float z2 = b2[lane];
#pragma unroll
    for (int h = 0; h < H_DIM; ++h)
        z2 = fmaf(__shfl(h1, h, 64), W2s[h * 65 + lane], z2);

    float s2  = 1.f / (1.f + exp2f(-z2 * LOG2E));
    float w3  = W3[lane];
    float Fp  = z2 * s2 * w3;
    float dz2 = w3 * s2 * fmaf(z2, 1.f - s2, 1.f);

    float dh1 = 0.f;
#pragma unroll
    for (int j = 0; j < H_DIM; ++j)
        dh1 = fmaf(__shfl(dz2, j, 64), W2s[lane * 65 + j], dh1);

    float Gp = dh1 * ds1 * u;
#pragma unroll
    for (int m = 32; m > 0; m >>= 1) {
        Fp += __shfl_xor(Fp, m, 64);
        Gp += __shfl_xor(Gp, m, 64);
    }
    if (lane == 0) tab[i] = make_float2(Fp + b3[0], Gp);
}

__global__ __launch_bounds__(256) void edge_fallback(
    const float* __restrict__ pos, const float* __restrict__ bond,
    const int* __restrict__ src, const int* __restrict__ dst,
    const float* __restrict__ volume, const float2* __restrict__ tab,
    float* __restrict__ out)
{
    __shared__ float red[4][10];
    int lb = (blockIdx.x & 7) * (N_EDGES / N_GRAPHS / 256) + (blockIdx.x >> 3);
    int g  = blockIdx.x & 7;
    int e  = lb * 256 + threadIdx.x;

    int si = src[e], di = dst[e];
    float bx = bond[3 * e + 0], by = bond[3 * e + 1], bz = bond[3 * e + 2];
    float dx = bx + pos[3 * di + 0] - pos[3 * si + 0];
    float dy = by + pos[3 * di + 1] - pos[3 * si + 1];
    float dz = bz + pos[3 * di + 2] - pos[3 * si + 2];
    float d  = sqrtf(fmaf(dx, dx, fmaf(dy, dy, fmaf(dz, dz, 1e-12f))));

    float tt  = fminf(d * ((float)TBL / D_MAX), (float)(TBL - 1));
    int   ix  = min((int)tt, TBL - 2);
    float fr  = tt - (float)ix;
    float2 ta = tab[ix], tb2 = tab[ix + 1];
    float F = fmaf(fr, tb2.x - ta.x, ta.x);
    float G = fmaf(fr, tb2.y - ta.y, ta.y);
    float scl = G / d;
    float gx = scl * dx, gy = scl * dy, gz = scl * dz;

    float* forces = out + OUT_FORCES;
    atomicAdd(forces + 3 * di + 0, -gx);
    atomicAdd(forces + 3 * di + 1, -gy);
    atomicAdd(forces + 3 * di + 2, -gz);
    atomicAdd(forces + 3 * si + 0,  gx);
    atomicAdd(forces + 3 * si + 1,  gy);
    atomicAdd(forces + 3 * si + 2,  gz);

    float v[10] = { F,
                    bx * gx, bx * gy, bx * gz,
                    by * gx, by * gy, by * gz,
                    bz * gx, bz * gy, bz * gz };
#pragma unroll
    for (int q = 0; q < 10; ++q) {
        float x = v[q];
#pragma unroll
        for (int m = 32; m > 0; m >>= 1) x += __shfl_xor(x, m, 64);
        v[q] = x;
    }
    int wave = threadIdx.x >> 6;
    if ((threadIdx.x & 63) == 0)
#pragma unroll
        for (int q = 0; q < 10; ++q) red[wave][q] = v[q];
    __syncthreads();
    if (threadIdx.x < 10) {
        float tot = red[0][threadIdx.x] + red[1][threadIdx.x]
                  + red[2][threadIdx.x] + red[3][threadIdx.x];
        if (threadIdx.x == 0) atomicAdd(out + g, tot);
        else {
            float vol = volume[g * NODES_PER_GRAPH];
            atomicAdd(out + OUT_STRESS + g * 9 + (threadIdx.x - 1),
                      tot * (EV_A3_TO_GPA / vol));
        }
    }
}

extern "C" void kernel_launch(void* const* d_in, const int* in_sizes, int n_in,
                              void* d_out, int out_size, void* d_ws, size_t ws_size,
                              hipStream_t stream)
{
    const float* pos     = (const float*)d_in[0];
    const float* bond    = (const float*)d_in[1];
    const int*   src     = (const int*)d_in[2];
    const int*   dst     = (const int*)d_in[3];
    // d_in[4] = edge_graph (implicit: edges contiguous per graph)
    const float* volume  = (const float*)d_in[5];
    const float* centers = (const float*)d_in[6];
    const float* W1 = (const float*)d_in[7];
    const float* b1 = (const float*)d_in[8];
    const float* W2 = (const float*)d_in[9];
    const float* b2 = (const float*)d_in[10];
    const float* W3 = (const float*)d_in[11];
    const float* b3 = (const float*)d_in[12];
    float*  out  = (float*)d_out;
    char*   ws   = (char*)d_ws;
    float2* tab  = (float2*)(ws + OFF_TAB);
    int*    ctl  = (int*)(ws + OFF_CTL);
    float4* recs = (float4*)(ws + OFF_REC);

    if (ws_size >= WS_NEED) {
        fused_all<<<NBLOCKS, NTHREADS, 0, stream>>>(
            pos, bond, src, dst, volume, centers,
            W1, b1, W2, b2, W3, b3, tab, ctl, recs, out);
    } else {
        hipMemsetAsync(d_out, 0, (size_t)out_size * sizeof(float), stream);
        build_table_fb<<<TBL / 4, 256, 0, stream>>>(centers, W1, b1, W2, b2,
                                                    W3, b3, tab);
        edge_fallback<<<N_EDGES / 256, 256, 0, stream>>>(
            pos, bond, src, dst, volume, tab, out);
    }
}

// Round 8
// 149.739 us; speedup vs baseline: 2.6724x; 2.6724x over previous
//
#include <hip/hip_runtime.h>
#include <math.h>

#define K_RBF 32
#define H_DIM 64
#define TBL 4096
#define D_MAX 16.0f
#define N_NODES 49152
#define N_EDGES 786432
#define N_GRAPHS 8
#define NODES_PER_GRAPH 6144
#define EV_A3_TO_GPA 160.21766208f
#define LOG2E 1.44269504088896f

// out layout: energies[8] | forces[147456] | stresses[72] | hessian[1]
#define OUT_FORCES 8
#define OUT_STRESS 147464
#define OUT_TAIL_N 81

// force binning: 256 chunks x 192 nodes (576 floats = 2.3 KB LDS acc);
// 256 scatter blocks -> one per chunk -> LDS-atomic pipe spread over ~all CUs
// (R6 measured ~3 cyc/LDS-atomic per CU; 4.72M atomics / 256 CUs ~= 23 us).
#define CHUNK_NODES  192
#define CHUNK_FLOATS 576
#define N_CHUNKS     256
#define REC_CAP      7168        // mean 6144, sigma ~78 -> +13 sigma

// edge geometry: 384 blocks x 1024 thr x 2 edges; 48 blocks per graph
#define EDGE_BLOCKS   384
#define EDGE_THREADS  1024
#define EDGES_PER_GRAPH (N_EDGES / N_GRAPHS)   // 98304
#define BLK_PER_GRAPH 48                       // 98304 / 2048

// ws layout (bytes): tab 32 KB | gcnt 1 KB | records 29.4 MB
#define OFF_TAB 0u
#define OFF_CNT 32768u
#define OFF_REC 33792u
#define WS_NEED (OFF_REC + (size_t)N_CHUNKS * REC_CAP * 16u)

// chunk index: node/192 = (node>>6)/3 via mul-shift (exact for node < 49152)
__device__ __forceinline__ int chunk_of(int node) {
    return (int)((unsigned)((node >> 6) * 683) >> 11);
}

// -------- Kernel 1: tabulate F(d)=e_edge(d), G(d)=dE/dd — wave-per-entry ----
__global__ __launch_bounds__(256) void build_table(
    const float* __restrict__ centers,
    const float* __restrict__ W1, const float* __restrict__ b1,
    const float* __restrict__ W2, const float* __restrict__ b2,
    const float* __restrict__ W3, const float* __restrict__ b3,
    float2* __restrict__ tab, int* __restrict__ gcnt,
    float* __restrict__ out, int zero_out_tail)
{
    // fold bookkeeping init into this (tiny) dispatch
    if (blockIdx.x == 0) {
        int t = threadIdx.x;
        gcnt[t] = 0;                                        // 256 counters
        if (zero_out_tail) {
            if (t < N_GRAPHS) out[t] = 0.f;                 // energies
            else if (t < OUT_TAIL_N) out[3 * N_NODES + t] = 0.f; // stress+hess
        }
    }

    __shared__ float W2s[H_DIM * 65];
    for (int idx = threadIdx.x; idx < H_DIM * H_DIM; idx += 256)
        W2s[(idx >> 6) * 65 + (idx & 63)] = W2[idx];
    __syncthreads();

    int lane = threadIdx.x & 63;
    int i    = blockIdx.x * 4 + (threadIdx.x >> 6);
    float d  = (float)i * (D_MAX / (float)TBL);

    float z1 = b1[lane], u = 0.f;
#pragma unroll
    for (int k = 0; k < K_RBF; ++k) {
        float tc = d - centers[k];
        float e  = exp2f(-tc * tc * LOG2E);       // exp(-t^2)
        float w  = W1[k * H_DIM + lane];
        z1 = fmaf(e, w, z1);
        u  = fmaf(-2.f * tc * e, w, u);
    }
    float s1  = 1.f / (1.f + exp2f(-z1 * LOG2E));
    float h1  = z1 * s1;
    float ds1 = s1 * fmaf(z1, 1.f - s1, 1.f);     // silu'(z1)

    float z2 = b2[lane];
#pragma unroll
    for (int h = 0; h < H_DIM; ++h)
        z2 = fmaf(__shfl(h1, h, 64), W2s[h * 65 + lane], z2);

    float s2  = 1.f / (1.f + exp2f(-z2 * LOG2E));
    float w3  = W3[lane];
    float Fp  = z2 * s2 * w3;
    float dz2 = w3 * s2 * fmaf(z2, 1.f - s2, 1.f);

    float dh1 = 0.f;
#pragma unroll
    for (int j = 0; j < H_DIM; ++j)
        dh1 = fmaf(__shfl(dz2, j, 64), W2s[lane * 65 + j], dh1);

    float Gp = dh1 * ds1 * u;
#pragma unroll
    for (int m = 32; m > 0; m >>= 1) {
        Fp += __shfl_xor(Fp, m, 64);
        Gp += __shfl_xor(Gp, m, 64);
    }
    if (lane == 0) tab[i] = make_float2(Fp + b3[0], Gp);
}

// -------- Kernel 2: per-edge compute + 256-bin record emission ----------
__global__ __launch_bounds__(EDGE_THREADS) void edge_compute(
    const float* __restrict__ pos, const float* __restrict__ bond,
    const int* __restrict__ src, const int* __restrict__ dst,
    const float* __restrict__ volume, const float2* __restrict__ tab,
    float4* __restrict__ recs, int* __restrict__ gcnt,
    float* __restrict__ out)
{
    __shared__ int   cnt[N_CHUNKS];
    __shared__ int   basech[N_CHUNKS];
    __shared__ float red[16][10];

    const int t = threadIdx.x;
    if (t < N_CHUNKS) cnt[t] = 0;
    __syncthreads();

    // edges contiguous per graph; graph from block index
    const int g = blockIdx.x & 7;
    const int w = blockIdx.x >> 3;                 // 0..47
    const int base_e = g * EDGES_PER_GRAPH + w * (EDGE_THREADS * 2);

    float vacc[10];
#pragma unroll
    for (int q = 0; q < 10; ++q) vacc[q] = 0.f;

    int   edi[2], esi[2], es0[2], es1[2];
    float egx[2], egy[2], egz[2];

#pragma unroll
    for (int i = 0; i < 2; ++i) {
        int e  = base_e + i * EDGE_THREADS + t;
        int si = src[e], di = dst[e];
        float bx = bond[3 * e + 0], by = bond[3 * e + 1], bz = bond[3 * e + 2];
        float dx = bx + pos[3 * di + 0] - pos[3 * si + 0];
        float dy = by + pos[3 * di + 1] - pos[3 * si + 1];
        float dz = bz + pos[3 * di + 2] - pos[3 * si + 2];
        float d  = sqrtf(fmaf(dx, dx, fmaf(dy, dy, fmaf(dz, dz, 1e-12f))));

        float tt  = fminf(d * ((float)TBL / D_MAX), (float)(TBL - 1));
        int   ix  = min((int)tt, TBL - 2);
        float fr  = tt - (float)ix;
        float2 ta = tab[ix], tb2 = tab[ix + 1];
        float F = fmaf(fr, tb2.x - ta.x, ta.x);
        float G = fmaf(fr, tb2.y - ta.y, ta.y);

        float scl = G / d;                         // gbv = (dE/dd)/d * disp
        float gx = scl * dx, gy = scl * dy, gz = scl * dz;
        egx[i] = gx; egy[i] = gy; egz[i] = gz;
        edi[i] = di; esi[i] = si;
        es0[i] = atomicAdd(&cnt[chunk_of(di)], 1);
        es1[i] = atomicAdd(&cnt[chunk_of(si)], 1);

        vacc[0] += F;
        vacc[1] = fmaf(bx, gx, vacc[1]); vacc[2] = fmaf(bx, gy, vacc[2]);
        vacc[3] = fmaf(bx, gz, vacc[3]); vacc[4] = fmaf(by, gx, vacc[4]);
        vacc[5] = fmaf(by, gy, vacc[5]); vacc[6] = fmaf(by, gz, vacc[6]);
        vacc[7] = fmaf(bz, gx, vacc[7]); vacc[8] = fmaf(bz, gy, vacc[8]);
        vacc[9] = fmaf(bz, gz, vacc[9]);
    }
    __syncthreads();
    if (t < N_CHUNKS) basech[t] = atomicAdd(&gcnt[t], cnt[t]);
    __syncthreads();
#pragma unroll
    for (int i = 0; i < 2; ++i) {
        int c0 = chunk_of(edi[i]), c1 = chunk_of(esi[i]);
        int l0 = edi[i] - c0 * CHUNK_NODES;
        int l1 = esi[i] - c1 * CHUNK_NODES;
        int p0 = basech[c0] + es0[i];
        int p1 = basech[c1] + es1[i];
        if (p0 < REC_CAP)   // dst gets -g (forces = -gpos)
            recs[(size_t)c0 * REC_CAP + p0] =
                make_float4(-egx[i], -egy[i], -egz[i], __int_as_float(l0));
        if (p1 < REC_CAP)   // src gets +g
            recs[(size_t)c1 * REC_CAP + p1] =
                make_float4(egx[i], egy[i], egz[i], __int_as_float(l1));
    }

    // block-level energy+stress reduce (all edges in block share graph g)
#pragma unroll
    for (int q = 0; q < 10; ++q) {
        float x = vacc[q];
#pragma unroll
        for (int m = 32; m > 0; m >>= 1) x += __shfl_xor(x, m, 64);
        vacc[q] = x;
    }
    int wave = t >> 6;
    if ((t & 63) == 0)
#pragma unroll
        for (int q = 0; q < 10; ++q) red[wave][q] = vacc[q];
    __syncthreads();
    if (t < 10) {
        float tot = 0.f;
#pragma unroll
        for (int k = 0; k < 16; ++k) tot += red[k][t];
        if (t == 0) atomicAdd(out + g, tot);
        else {
            float vol = volume[g * NODES_PER_GRAPH];
            atomicAdd(out + OUT_STRESS + g * 9 + (t - 1),
                      tot * (EV_A3_TO_GPA / vol));
        }
    }
}

// -------- Kernel 3: one block per chunk — LDS accumulate, final forces ------
__global__ __launch_bounds__(512) void scatter_direct(
    const float4* __restrict__ recs, const int* __restrict__ gcnt,
    float* __restrict__ out)
{
    __shared__ float acc[CHUNK_FLOATS];     // 2.3 KB
    const int t = threadIdx.x;
    if (t < CHUNK_FLOATS) acc[t] = 0.f;
    if (t < CHUNK_FLOATS - 512) acc[512 + t] = 0.f;
    __syncthreads();

    const int c = blockIdx.x;
    int total = min(gcnt[c], REC_CAP);
    const float4* seg = recs + (size_t)c * REC_CAP;
    for (int r = t; r < total; r += 512) {
        float4 rec = seg[r];
        int li = 3 * __float_as_int(rec.w);
        atomicAdd(&acc[li + 0], rec.x);
        atomicAdd(&acc[li + 1], rec.y);
        atomicAdd(&acc[li + 2], rec.z);
    }
    __syncthreads();

    if (t < CHUNK_FLOATS / 4) {
        float4* dst4 = (float4*)(out + OUT_FORCES + c * CHUNK_FLOATS);
        dst4[t] = ((const float4*)acc)[t];
    }
}

// -------- Fallback (ws too small): device-atomic path ----------
__global__ __launch_bounds__(256) void edge_fallback(
    const float* __restrict__ pos, const float* __restrict__ bond,
    const int* __restrict__ src, const int* __restrict__ dst,
    const float* __restrict__ volume, const float2* __restrict__ tab,
    float* __restrict__ out)
{
    __shared__ float red[4][10];
    int lb = (blockIdx.x & 7) * (EDGES_PER_GRAPH / 256) + (blockIdx.x >> 3);
    int g  = blockIdx.x & 7;
    int e  = lb * 256 + threadIdx.x;

    int si = src[e], di = dst[e];
    float bx = bond[3 * e + 0], by = bond[3 * e + 1], bz = bond[3 * e + 2];
    float dx = bx + pos[3 * di + 0] - pos[3 * si + 0];
    float dy = by + pos[3 * di + 1] - pos[3 * si + 1];
    float dz = bz + pos[3 * di + 2] - pos[3 * si + 2];
    float d  = sqrtf(fmaf(dx, dx, fmaf(dy, dy, fmaf(dz, dz, 1e-12f))));

    float tt  = fminf(d * ((float)TBL / D_MAX), (float)(TBL - 1));
    int   ix  = min((int)tt, TBL - 2);
    float fr  = tt - (float)ix;
    float2 ta = tab[ix], tb2 = tab[ix + 1];
    float F = fmaf(fr, tb2.x - ta.x, ta.x);
    float G = fmaf(fr, tb2.y - ta.y, ta.y);
    float scl = G / d;
    float gx = scl * dx, gy = scl * dy, gz = scl * dz;

    float* forces = out + OUT_FORCES;
    atomicAdd(forces + 3 * di + 0, -gx);
    atomicAdd(forces + 3 * di + 1, -gy);
    atomicAdd(forces + 3 * di + 2, -gz);
    atomicAdd(forces + 3 * si + 0,  gx);
    atomicAdd(forces + 3 * si + 1,  gy);
    atomicAdd(forces + 3 * si + 2,  gz);

    float v[10] = { F,
                    bx * gx, bx * gy, bx * gz,
                    by * gx, by * gy, by * gz,
                    bz * gx, bz * gy, bz * gz };
#pragma unroll
    for (int q = 0; q < 10; ++q) {
        float x = v[q];
#pragma unroll
        for (int m = 32; m > 0; m >>= 1) x += __shfl_xor(x, m, 64);
        v[q] = x;
    }
    int wave = threadIdx.x >> 6;
    if ((threadIdx.x & 63) == 0)
#pragma unroll
        for (int q = 0; q < 10; ++q) red[wave][q] = v[q];
    __syncthreads();
    if (threadIdx.x < 10) {
        float tot = red[0][threadIdx.x] + red[1][threadIdx.x]
                  + red[2][threadIdx.x] + red[3][threadIdx.x];
        if (threadIdx.x == 0) atomicAdd(out + g, tot);
        else {
            float vol = volume[g * NODES_PER_GRAPH];
            atomicAdd(out + OUT_STRESS + g * 9 + (threadIdx.x - 1),
                      tot * (EV_A3_TO_GPA / vol));
        }
    }
}

extern "C" void kernel_launch(void* const* d_in, const int* in_sizes, int n_in,
                              void* d_out, int out_size, void* d_ws, size_t ws_size,
                              hipStream_t stream)
{
    const float* pos     = (const float*)d_in[0];
    const float* bond    = (const float*)d_in[1];
    const int*   src     = (const int*)d_in[2];
    const int*   dst     = (const int*)d_in[3];
    // d_in[4] = edge_graph (implicit: edges contiguous per graph)
    const float* volume  = (const float*)d_in[5];
    const float* centers = (const float*)d_in[6];
    const float* W1 = (const float*)d_in[7];
    const float* b1 = (const float*)d_in[8];
    const float* W2 = (const float*)d_in[9];
    const float* b2 = (const float*)d_in[10];
    const float* W3 = (const float*)d_in[11];
    const float* b3 = (const float*)d_in[12];
    float*  out  = (float*)d_out;
    char*   ws   = (char*)d_ws;
    float2* tab  = (float2*)(ws + OFF_TAB);
    int*    gcnt = (int*)(ws + OFF_CNT);
    float4* recs = (float4*)(ws + OFF_REC);

    if (ws_size >= WS_NEED) {
        build_table<<<TBL / 4, 256, 0, stream>>>(centers, W1, b1, W2, b2, W3, b3,
                                                 tab, gcnt, out, 1);
        edge_compute<<<EDGE_BLOCKS, EDGE_THREADS, 0, stream>>>(
            pos, bond, src, dst, volume, tab, recs, gcnt, out);
        scatter_direct<<<N_CHUNKS, 512, 0, stream>>>(recs, gcnt, out);
    } else {
        hipMemsetAsync(d_out, 0, (size_t)out_size * sizeof(float), stream);
        build_table<<<TBL / 4, 256, 0, stream>>>(centers, W1, b1, W2, b2, W3, b3,
                                                 tab, gcnt, out, 0);
        edge_fallback<<<N_EDGES / 256, 256, 0, stream>>>(
            pos, bond, src, dst, volume, tab, out);
    }
}